// Round 15
// baseline (112.546 us; speedup 1.0000x reference)
//
#include <hip/hip_runtime.h>
#include <math.h>
#include <stdint.h>

#define BROWS 262144
#define KCLS  101
#define ROWB  404
#define RPB   16                      // rows per batch (per wave)
#define BATCHB (RPB * ROWB)           // 6464 B
#define STAGEB 7168                   // 7 x 1KB staging issues (704 B pad)
#define TOTB  (BROWS * ROWB)          // 105,906,176 B
#define NBLK  2048                    // 8 blocks/CU resident (r12-validated optimum)
#define NBPW  8                       // batches per block

typedef const __attribute__((address_space(1))) uint32_t* gptr_t;
typedef __attribute__((address_space(3))) uint32_t*       lptr_t;

// Stage one 16-row batch (6464 B real, 7168 staged) into LDS.
__device__ __forceinline__ void stage_batch(const char* base, unsigned off,
                                            char* dst, int lane) {
#pragma unroll
    for (int k = 0; k < 7; ++k) {
        unsigned o = off + (unsigned)(k * 1024 + lane * 16);
        o = (o > (unsigned)(TOTB - 16)) ? (unsigned)(TOTB - 16) : o;
        __builtin_amdgcn_global_load_lds((gptr_t)(base + o),
                                         (lptr_t)(dst + k * 1024), 16, 0, 0);
    }
}

// 4 lanes per row: lane q owns classes [25q, 25q+n), n = 25,25,25,26.
// All terms lane-local streams; prefix-offset algebra merges the 4 lanes.
// Single-wave blocks, counted vmcnt(7), no barriers. Fused finish: last
// block (ticket) re-reduces all partials in fixed order -> deterministic.
extern "C" __global__ void __launch_bounds__(64)
ord_main(const float* __restrict__ logit,
         const int*   __restrict__ labels,
         const float* __restrict__ cw,
         float*       __restrict__ partial,
         unsigned*    __restrict__ ticket,
         float*       __restrict__ out)
{
    __shared__ __align__(16) char  smem[2 * STAGEB];   // 14336 B
    __shared__ __align__(16) int   ylds[128];          // 8 batches x 16 labels
    __shared__ __align__(16) float cwlds[128];         // 101 weights (+pad)

    const int lane = threadIdx.x;
    const int q    = lane & 3;
    const int g    = lane >> 2;                        // row within batch, 0..15
    const char* gb = (const char*)logit;
    const unsigned woff = (unsigned)blockIdx.x * (unsigned)(RPB * NBPW * ROWB);

    // ---- prologue staging (11 vmcnt-tracked issues) ----
    stage_batch(gb, woff, smem, lane);
    {
        const char* lb = (const char*)labels + (size_t)blockIdx.x * (RPB * NBPW * 4);
        __builtin_amdgcn_global_load_lds((gptr_t)(lb + lane * 4), (lptr_t)ylds, 4, 0, 0);
        __builtin_amdgcn_global_load_lds((gptr_t)(lb + 256 + lane * 4),
                                         (lptr_t)((char*)ylds + 256), 4, 0, 0);
        const char* cwb = (const char*)cw;
        unsigned o1 = 256u + (unsigned)(lane * 4); o1 = (o1 > 400u) ? 400u : o1;
        __builtin_amdgcn_global_load_lds((gptr_t)(cwb + lane * 4), (lptr_t)cwlds, 4, 0, 0);
        __builtin_amdgcn_global_load_lds((gptr_t)(cwb + o1),
                                         (lptr_t)((char*)cwlds + 256), 4, 0, 0);
    }

    const float inv_logK = 1.0f / logf(101.0f);        // folds at compile time
    const float invK     = 1.0f / 101.0f;
    const int   t0 = 25 * q;
    const int   nn = (q == 3) ? 26 : 25;
    const float nq = (float)nn;

    float tacc = 0.0f;

    for (int k = 0; k < NBPW; ++k) {
        if (k + 1 < NBPW) {
            stage_batch(gb, woff + (unsigned)((k + 1) * BATCHB),
                        smem + ((k + 1) & 1) * STAGEB, lane);
            asm volatile("s_waitcnt vmcnt(7)" ::: "memory");  // batch k ready; prefetch flying
        } else {
            asm volatile("s_waitcnt vmcnt(0)" ::: "memory");
        }

        const float* rowb = (const float*)(smem + (k & 1) * STAGEB) + g * KCLS;
        const float* lrow = rowb + t0;
        const int    y    = ylds[k * 16 + g];
        const float  wy   = cwlds[y];
        const float  yf   = (float)y;

        // ---- lane-local stream over 25 (+1 for q==3) classes ----
        float a = 0.f, w = 0.f, sp = 0.f, tl = 0.f, bm = 0.f, cm = 0.f;
        float us = 0.f, ef = 0.f, ep = 0.f;
#pragma unroll
        for (int i = 0; i < 25; ++i) {
            const int   t = t0 + i;
            const float e = __expf(lrow[i]);           // no max-shift: |x| < ~6
            if (i == 0) ef = e; else us += __builtin_fabsf(e - ep);
            a += e;                                    // local inclusive prefix L_i
            w += a;                                    // sum L_i
            sp = __builtin_fmaf(a, a, sp);             // sum L_i^2
            tl += (t <= y) ? a : 0.0f;                 // masked sum L_i
            bm = __builtin_fmaf(e, (float)t, bm);      // sum e*t
            cm = __builtin_fmaf(e, (float)(t * t), cm);// sum e*t^2
            ep = e;
        }
        if (q == 3) {                                  // class 100
            const float e = __expf(lrow[25]);
            us += __builtin_fabsf(e - ep);
            a += e; w += a;
            sp = __builtin_fmaf(a, a, sp);
            tl += (y >= 100) ? a : 0.0f;
            bm = __builtin_fmaf(e, 100.0f, bm);
            cm = __builtin_fmaf(e, 10000.0f, cm);
            ep = e;
        }

        // ---- 4-lane merge ----
        float incl = a;
        { float u = __shfl_up(incl, 1, 4); incl += (q >= 1) ? u : 0.0f; }
        { float u = __shfl_up(incl, 2, 4); incl += (q >= 2) ? u : 0.0f; }
        const float S   = __shfl(incl, 3, 4);          // row total
        const float E   = incl - a;                    // exclusive e-prefix
        const float inv = __builtin_amdgcn_rcpf(S);
        const float nf  = __shfl_down(ef, 1, 4);       // next lane's first e (q==3 junk)

        int mi = y - t0 + 1; mi = (mi < 0) ? 0 : mi; mi = (mi > nn) ? nn : mi;
        const float spc  = __builtin_fmaf(nq * E, E, __builtin_fmaf(2.0f * E, w, sp));
        const float tlc  = __builtin_fmaf((float)mi, E, tl);
        const float eseC = __builtin_fmaf(yf, __builtin_fmaf(yf, a, -2.0f * bm), cm);
        const float uniC = us + ((q < 3) ? __builtin_fabsf(ep - nf) : 0.0f)
                         + ((q == 0) ? ef : 0.0f) + ((q == 3) ? ep : 0.0f);

        float part = (wy * 1.0e-4f * inv) * eseC;              // ESE
        part = __builtin_fmaf(invK * inv * inv, spc, part);    // EMD quad
        part = __builtin_fmaf(-2.0f * invK * inv, tlc, part);  // EMD cross
        part = __builtin_fmaf(0.00375f * inv, uniC, part);     // uni |delta|
        part += __shfl_xor(part, 1);
        part += __shfl_xor(part, 2);                           // group total

        // ---- epilogue (broadcast LDS reads; only q==0 accumulates) ----
        const int   ym = (y > 0)   ? y - 1 : 0;
        const int   yp = (y < 100) ? y + 1 : 100;
        const float xy = rowb[y];
        const float eY = __expf(xy);
        const float eL = (y > 0)   ? __expf(rowb[ym]) : 0.0f;
        const float eR = (y < 100) ? __expf(rowb[yp]) : 0.0f;
        const float lnS  = __logf(S);
        const float py   = eY * inv;
        const float tail = 1.0f - (eL + eY + eR) * inv;
        const float lp   = fmaxf(__builtin_fmaf(fmaxf(eL, eR), inv, 0.25f - py), 0.0f);
        const float extra = wy * (lnS - xy) * inv_logK         // CE
                          + 2.5f * (tail + lp)                 // tail + local peak
                          - 0.0075f * py                       // uni -2*cU*p_y
                          + invK * (float)(y + 1);             // EMD scalar remainder

        tacc += (q == 0) ? (part + extra) : 0.0f;
    }

    // ---- single-wave butterfly (deterministic) ----
    tacc += __shfl_xor(tacc, 1);
    tacc += __shfl_xor(tacc, 2);
    tacc += __shfl_xor(tacc, 4);
    tacc += __shfl_xor(tacc, 8);
    tacc += __shfl_xor(tacc, 16);
    tacc += __shfl_xor(tacc, 32);

    if (lane == 0) partial[blockIdx.x] = tacc;

    // ---- fused finish: last block reduces all partials (fixed order) ----
    __threadfence();                                   // publish partial before ticket
    unsigned done = 0;
    if (lane == 0) {
        const unsigned old = atomicAdd(ticket, 1u);
        done = (old == (unsigned)(NBLK - 1)) ? 1u : 0u;
    }
    done = (unsigned)__shfl((int)done, 0, 64);
    if (done) {
        __threadfence();                               // acquire: see all partials
        volatile const float* vp = (volatile const float*)partial;
        float v = 0.0f;
#pragma unroll
        for (int k2 = 0; k2 < NBLK / 64; ++k2)         // fixed order: k2 asc, lane-local
            v += vp[k2 * 64 + lane];
        v += __shfl_xor(v, 1);
        v += __shfl_xor(v, 2);
        v += __shfl_xor(v, 4);
        v += __shfl_xor(v, 8);
        v += __shfl_xor(v, 16);
        v += __shfl_xor(v, 32);
        if (lane == 0) out[0] = v * (1.0f / (float)BROWS);
    }
}

extern "C" void kernel_launch(void* const* d_in, const int* in_sizes, int n_in,
                              void* d_out, int out_size, void* d_ws, size_t ws_size,
                              hipStream_t stream)
{
    const float* logit  = (const float*)d_in[0];
    const int*   labels = (const int*)d_in[1];
    const float* cw     = (const float*)d_in[2];
    float*       part   = (float*)d_ws;
    unsigned*    ticket = (unsigned*)((char*)d_ws + (size_t)NBLK * sizeof(float));

    // zero the ticket each call (graph-capturable async memset on stream)
    hipMemsetAsync(ticket, 0, sizeof(unsigned), stream);

    hipLaunchKernelGGL(ord_main, dim3(NBLK), dim3(64), 0, stream,
                       logit, labels, cw, part, ticket, (float*)d_out);
}

// Round 16
// 32.223 us; speedup vs baseline: 3.4928x; 3.4928x over previous
//
#include <hip/hip_runtime.h>
#include <math.h>
#include <stdint.h>

#define BROWS 262144
#define KCLS  101
#define ROWB  404
#define RPB   16                      // rows per batch
#define BATCHB (RPB * ROWB)           // 6464 B
#define STAGEB 7168                   // 7 x 1KB staging issues (704 B pad)
#define TOTB  (BROWS * ROWB)          // 105,906,176 B
#define NBT   (BROWS / RPB)           // 16384 batches
#define NBLK  2560                    // 10 blocks/CU (LDS cap) — grid-stride batches
#define LBLB  (BROWS * 4)             // labels bytes

typedef const __attribute__((address_space(1))) uint32_t* gptr_t;
typedef __attribute__((address_space(3))) uint32_t*       lptr_t;

// Stage one 16-row batch (6464 B real, 7168 staged) into LDS.
__device__ __forceinline__ void stage_batch(const char* base, unsigned off,
                                            char* dst, int lane) {
#pragma unroll
    for (int k = 0; k < 7; ++k) {
        unsigned o = off + (unsigned)(k * 1024 + lane * 16);
        o = (o > (unsigned)(TOTB - 16)) ? (unsigned)(TOTB - 16) : o;
        __builtin_amdgcn_global_load_lds((gptr_t)(base + o),
                                         (lptr_t)(dst + k * 1024), 16, 0, 0);
    }
}

// 4 lanes per row: lane q owns classes [25q, 25q+n), n = 25,25,25,26.
// Lane-local streams + prefix-offset merge (r12-validated math, absmax 0.0).
// Single-wave blocks, no barriers, counted vmcnt(8) (7 data + 1 labels).
// r15 lesson: NO per-block device fences/atomics (cost ~90 us at 2048 blocks);
// two-kernel finish is the cheap structure.
extern "C" __global__ void __launch_bounds__(64)
ord_main(const float* __restrict__ logit,
         const int*   __restrict__ labels,
         const float* __restrict__ cw,
         float*       __restrict__ partial)
{
    __shared__ __align__(16) char  smem[2 * STAGEB];   // 14336 B
    __shared__ __align__(16) int   ylds[2][64];        // 512 B (dbuf, 16 used/slot)
    __shared__ __align__(16) float cwlds[128];         // 512 B (101 + pad)

    const int lane = threadIdx.x;
    const int q    = lane & 3;
    const int g    = lane >> 2;                        // row within batch, 0..15
    const char* gb = (const char*)logit;
    const char* lb = (const char*)labels;

    // per-batch label stage: 64 lanes x 4B = 256 B (48 overread, clamped, unread)
    auto stage_labels = [&](int bt, int buf) {
        unsigned o = (unsigned)bt * 64u + (unsigned)(lane * 4);
        o = (o > (unsigned)(LBLB - 4)) ? (unsigned)(LBLB - 4) : o;
        __builtin_amdgcn_global_load_lds((gptr_t)(lb + o), (lptr_t)&ylds[buf][0], 4, 0, 0);
    };

    const int bt0 = blockIdx.x;

    // ---- prologue: batch bt0 data + labels, class weights (10 issues) ----
    stage_batch(gb, (unsigned)bt0 * (unsigned)BATCHB, smem, lane);
    stage_labels(bt0, 0);
    {
        const char* cwb = (const char*)cw;
        unsigned o1 = 256u + (unsigned)(lane * 4); o1 = (o1 > 400u) ? 400u : o1;
        __builtin_amdgcn_global_load_lds((gptr_t)(cwb + lane * 4), (lptr_t)cwlds, 4, 0, 0);
        __builtin_amdgcn_global_load_lds((gptr_t)(cwb + o1),
                                         (lptr_t)((char*)cwlds + 256), 4, 0, 0);
    }

    const float inv_logK = 1.0f / logf(101.0f);        // folds at compile time
    const float invK     = 1.0f / 101.0f;
    const int   t0 = 25 * q;
    const int   nn = (q == 3) ? 26 : 25;
    const float nq = (float)nn;

    float tacc = 0.0f;
    int cur = 0;

    for (int bt = bt0; bt < NBT; bt += NBLK) {
        const int nxt = bt + NBLK;
        if (nxt < NBT) {
            stage_batch(gb, (unsigned)nxt * (unsigned)BATCHB,
                        smem + (cur ^ 1) * STAGEB, lane);
            stage_labels(nxt, cur ^ 1);
            // 8 just-issued remain in flight; batch bt (data+labels+cw) drained
            asm volatile("s_waitcnt vmcnt(8)" ::: "memory");
        } else {
            asm volatile("s_waitcnt vmcnt(0)" ::: "memory");
        }

        const float* rowb = (const float*)(smem + cur * STAGEB) + g * KCLS;
        const float* lrow = rowb + t0;
        const int    y    = ylds[cur][g];
        const float  wy   = cwlds[y];
        const float  yf   = (float)y;

        // ---- lane-local stream over 25 (+1 for q==3) classes ----
        float a = 0.f, w = 0.f, sp = 0.f, tl = 0.f, bm = 0.f, cm = 0.f;
        float us = 0.f, ef = 0.f, ep = 0.f;
#pragma unroll
        for (int i = 0; i < 25; ++i) {
            const int   t = t0 + i;
            const float e = __expf(lrow[i]);           // no max-shift: |x| < ~6
            if (i == 0) ef = e; else us += __builtin_fabsf(e - ep);
            a += e;                                    // local inclusive prefix L_i
            w += a;                                    // sum L_i
            sp = __builtin_fmaf(a, a, sp);             // sum L_i^2
            tl += (t <= y) ? a : 0.0f;                 // masked sum L_i
            bm = __builtin_fmaf(e, (float)t, bm);      // sum e*t
            cm = __builtin_fmaf(e, (float)(t * t), cm);// sum e*t^2
            ep = e;
        }
        if (q == 3) {                                  // class 100
            const float e = __expf(lrow[25]);
            us += __builtin_fabsf(e - ep);
            a += e; w += a;
            sp = __builtin_fmaf(a, a, sp);
            tl += (y >= 100) ? a : 0.0f;
            bm = __builtin_fmaf(e, 100.0f, bm);
            cm = __builtin_fmaf(e, 10000.0f, cm);
            ep = e;
        }

        // ---- 4-lane merge ----
        float incl = a;
        { float u = __shfl_up(incl, 1, 4); incl += (q >= 1) ? u : 0.0f; }
        { float u = __shfl_up(incl, 2, 4); incl += (q >= 2) ? u : 0.0f; }
        const float S   = __shfl(incl, 3, 4);          // row total
        const float E   = incl - a;                    // exclusive e-prefix
        const float inv = __builtin_amdgcn_rcpf(S);
        const float nf  = __shfl_down(ef, 1, 4);       // next lane's first e (q==3 junk)

        int mi = y - t0 + 1; mi = (mi < 0) ? 0 : mi; mi = (mi > nn) ? nn : mi;
        const float spc  = __builtin_fmaf(nq * E, E, __builtin_fmaf(2.0f * E, w, sp));
        const float tlc  = __builtin_fmaf((float)mi, E, tl);
        const float eseC = __builtin_fmaf(yf, __builtin_fmaf(yf, a, -2.0f * bm), cm);
        const float uniC = us + ((q < 3) ? __builtin_fabsf(ep - nf) : 0.0f)
                         + ((q == 0) ? ef : 0.0f) + ((q == 3) ? ep : 0.0f);

        float part = (wy * 1.0e-4f * inv) * eseC;              // ESE
        part = __builtin_fmaf(invK * inv * inv, spc, part);    // EMD quad
        part = __builtin_fmaf(-2.0f * invK * inv, tlc, part);  // EMD cross
        part = __builtin_fmaf(0.00375f * inv, uniC, part);     // uni |delta|
        part += __shfl_xor(part, 1);
        part += __shfl_xor(part, 2);                           // group total

        // ---- epilogue (broadcast LDS reads; only q==0 accumulates) ----
        const int   ym = (y > 0)   ? y - 1 : 0;
        const int   yp = (y < 100) ? y + 1 : 100;
        const float xy = rowb[y];
        const float eY = __expf(xy);
        const float eL = (y > 0)   ? __expf(rowb[ym]) : 0.0f;
        const float eR = (y < 100) ? __expf(rowb[yp]) : 0.0f;
        const float lnS  = __logf(S);
        const float py   = eY * inv;
        const float tail = 1.0f - (eL + eY + eR) * inv;
        const float lp   = fmaxf(__builtin_fmaf(fmaxf(eL, eR), inv, 0.25f - py), 0.0f);
        const float extra = wy * (lnS - xy) * inv_logK         // CE
                          + 2.5f * (tail + lp)                 // tail + local peak
                          - 0.0075f * py                       // uni -2*cU*p_y
                          + invK * (float)(y + 1);             // EMD scalar remainder

        tacc += (q == 0) ? (part + extra) : 0.0f;
        cur ^= 1;
    }

    // ---- single-wave butterfly (deterministic) ----
    tacc += __shfl_xor(tacc, 1);
    tacc += __shfl_xor(tacc, 2);
    tacc += __shfl_xor(tacc, 4);
    tacc += __shfl_xor(tacc, 8);
    tacc += __shfl_xor(tacc, 16);
    tacc += __shfl_xor(tacc, 32);

    if (lane == 0) partial[blockIdx.x] = tacc;
}

extern "C" __global__ void __launch_bounds__(256)
ord_final(const float* __restrict__ partial, float* __restrict__ out, int n)
{
    float v = 0.0f;
    for (int i = threadIdx.x; i < n; i += 256) v += partial[i];

    v += __shfl_xor(v, 1);
    v += __shfl_xor(v, 2);
    v += __shfl_xor(v, 4);
    v += __shfl_xor(v, 8);
    v += __shfl_xor(v, 16);
    v += __shfl_xor(v, 32);

    __shared__ float sb[4];
    const int lane = threadIdx.x & 63;
    const int wid  = threadIdx.x >> 6;
    if (lane == 0) sb[wid] = v;
    __syncthreads();
    if (threadIdx.x == 0)
        out[0] = ((sb[0] + sb[1]) + (sb[2] + sb[3])) * (1.0f / (float)BROWS);
}

extern "C" void kernel_launch(void* const* d_in, const int* in_sizes, int n_in,
                              void* d_out, int out_size, void* d_ws, size_t ws_size,
                              hipStream_t stream)
{
    const float* logit  = (const float*)d_in[0];
    const int*   labels = (const int*)d_in[1];
    const float* cw     = (const float*)d_in[2];
    float*       part   = (float*)d_ws;

    int NB = NBLK;
    if ((size_t)NB * sizeof(float) > ws_size) NB = (int)(ws_size / sizeof(float));
    if (NB > NBLK) NB = NBLK;
    if (NB < 1) NB = 1;
    // NB must equal the compiled grid-stride for correctness of batch coverage:
    // kernel strides by NBLK, so launch exactly NBLK blocks (ws guaranteed big).

    hipLaunchKernelGGL(ord_main, dim3(NBLK), dim3(64), 0, stream,
                       logit, labels, cw, part);
    hipLaunchKernelGGL(ord_final, dim3(1), dim3(256), 0, stream,
                       part, (float*)d_out, NBLK);
}